// Round 1
// baseline (212.337 us; speedup 1.0000x reference)
//
#include <hip/hip_runtime.h>

// SpatialTransformerPooled3d: x(16,64,16,64,64) f32, grid(1,2048,1,2),
// features(1,192,1,2048), bias(2048) -> out(16,16,2048) f32.
// b = n*16 + t indexes the 256 images; each image is 64ch x 64 x 64.
// out[b,p] = bias[p] + sum_{l=0..2} sum_{c=0..63} feat[l*64+c,p] * bilinear_l(img_l[b,c], pts[p])
// where img_l is the 2^l avg-pooled image.

namespace {

constexpr int B_ = 256;
constexpr int P_ = 2048;

// ws layout (float units)
constexpr long NV0 = 256L * 16 * 16 * 64;   // level0 window [24,40)^2, layout [b][yy][xx][c]
constexpr long NV1 = 256L * 8 * 8 * 64;     // level1 window [12,20)^2
constexpr long NV2 = 256L * 4 * 4 * 64;     // level2 window [6,10)^2
constexpr long NFT = 2048L * 192;           // features transposed: FT[p*192 + lc]
constexpr long OFF_V0 = 0;
constexpr long OFF_V1 = OFF_V0 + NV0;
constexpr long OFF_V2 = OFF_V1 + NV1;
constexpr long OFF_FT = OFF_V2 + NV2;
constexpr long OFF_WT = OFF_FT + NFT;       // float4 wtab[P_*3]
constexpr long OFF_OT = OFF_WT + 4L * P_ * 3; // int4 otab[P_*3]
constexpr long WS_FLOATS = OFF_OT + 4L * P_ * 3;
constexpr size_t WS_BYTES = (size_t)WS_FLOATS * 4;

__device__ __forceinline__ int xoff(int b, int c, int y, int xc) {
  // x index (n, c, t, y, xc); b = n*16 + t
  int n = b >> 4, t = b & 15;
  return (((n * 64 + c) * 16 + t) << 12) + (y << 6) + xc;
}

template <int L>
__device__ __forceinline__ float boxavg(const float* __restrict__ x, int b, int c,
                                        int yc, int xc) {
  constexpr int s = 1 << L;
  int base = xoff(b, c, yc * s, xc * s);
  float sum = 0.f;
#pragma unroll
  for (int dy = 0; dy < s; ++dy)
#pragma unroll
    for (int dx = 0; dx < s; ++dx) sum += x[base + dy * 64 + dx];
  return sum * (1.0f / (s * s));
}

// Bilinear tap coords + weights (validity folded into weights), per reference math.
__device__ __forceinline__ void taps_for(float gx, float gy, int Wl, float4& Wt,
                                         int2& xcv, int2& ycv) {
  float ix = ((gx + 1.f) * Wl - 1.f) * 0.5f;
  float iy = ((gy + 1.f) * Wl - 1.f) * 0.5f;
  float ix0f = floorf(ix), iy0f = floorf(iy);
  float fx1 = ix - ix0f, fy1 = iy - iy0f;
  float fx0 = 1.f - fx1, fy0 = 1.f - fy1;
  int ix0 = (int)ix0f, iy0 = (int)iy0f;
  int ix1 = ix0 + 1, iy1 = iy0 + 1;
  bool vx0 = (ix0 >= 0) && (ix0 < Wl);
  bool vx1 = (ix1 >= 0) && (ix1 < Wl);
  bool vy0 = (iy0 >= 0) && (iy0 < Wl);
  bool vy1 = (iy1 >= 0) && (iy1 < Wl);
  xcv.x = min(max(ix0, 0), Wl - 1);
  xcv.y = min(max(ix1, 0), Wl - 1);
  ycv.x = min(max(iy0, 0), Wl - 1);
  ycv.y = min(max(iy1, 0), Wl - 1);
  Wt.x = (vx0 && vy0) ? fx0 * fy0 : 0.f;  // tap (x0, y0)
  Wt.y = (vx1 && vy0) ? fx1 * fy0 : 0.f;  // tap (x1, y0)
  Wt.z = (vx0 && vy1) ? fx0 * fy1 : 0.f;  // tap (x0, y1)
  Wt.w = (vx1 && vy1) ? fx1 * fy1 : 0.f;  // tap (x1, y1)
}

__device__ __forceinline__ int enc(int xcv, int ycv, int O, int S, int Wl) {
  int xr = xcv - O, yr = ycv - O;
  if ((unsigned)xr < (unsigned)S && (unsigned)yr < (unsigned)S) return (yr * S + xr) * 64;
  return -1 - (ycv * Wl + xcv);  // out-of-window sentinel: encode clamped coords
}

__global__ __launch_bounds__(256) void st_prep(const float* __restrict__ x,
                                               const float* __restrict__ grid,
                                               const float* __restrict__ features,
                                               float* __restrict__ ws) {
  long idx = (long)blockIdx.x * 256 + threadIdx.x;
  if (idx < NV0) {  // level0 window copy (c-contiguous transpose)
    int c = (int)(idx & 63);
    long r = idx >> 6;
    int xx = (int)(r & 15), yy = (int)((r >> 4) & 15), b = (int)(r >> 8);
    ws[OFF_V0 + idx] = x[xoff(b, c, 24 + yy, 24 + xx)];
    return;
  }
  idx -= NV0;
  if (idx < NV1) {  // level1 = 2x2 mean
    int c = (int)(idx & 63);
    long r = idx >> 6;
    int xx = (int)(r & 7), yy = (int)((r >> 3) & 7), b = (int)(r >> 6);
    int base = xoff(b, c, (12 + yy) * 2, (12 + xx) * 2);
    ws[OFF_V1 + idx] = 0.25f * (x[base] + x[base + 1] + x[base + 64] + x[base + 65]);
    return;
  }
  idx -= NV1;
  if (idx < NV2) {  // level2 = 4x4 mean
    int c = (int)(idx & 63);
    long r = idx >> 6;
    int xx = (int)(r & 3), yy = (int)((r >> 2) & 3), b = (int)(r >> 4);
    int base = xoff(b, c, (6 + yy) * 4, (6 + xx) * 4);
    float s = 0.f;
#pragma unroll
    for (int dy = 0; dy < 4; ++dy)
#pragma unroll
      for (int dx = 0; dx < 4; ++dx) s += x[base + dy * 64 + dx];
    ws[OFF_V2 + idx] = s * (1.f / 16.f);
    return;
  }
  idx -= NV2;
  if (idx < NFT) {  // features transpose: FT[p*192+lc] = features[lc*2048+p]
    int lc = (int)(idx % 192);
    int p = (int)(idx / 192);
    ws[OFF_FT + idx] = features[(long)lc * 2048 + p];
    return;
  }
  idx -= NFT;
  if (idx < P_) {  // per-point tap tables
    int p = (int)idx;
    float gx = fminf(fmaxf(grid[2 * p], -1.f), 1.f);
    float gy = fminf(fmaxf(grid[2 * p + 1], -1.f), 1.f);
    float4* wt = (float4*)(ws + OFF_WT);
    int4* ot = (int4*)(ws + OFF_OT);
    const int winO[3] = {24, 12, 6};
    const int winS[3] = {16, 8, 4};
#pragma unroll
    for (int L = 0; L < 3; ++L) {
      int Wl = 64 >> L;
      float4 Wt;
      int2 xcv, ycv;
      taps_for(gx, gy, Wl, Wt, xcv, ycv);
      int4 O;
      O.x = enc(xcv.x, ycv.x, winO[L], winS[L], Wl);
      O.y = enc(xcv.y, ycv.x, winO[L], winS[L], Wl);
      O.z = enc(xcv.x, ycv.y, winO[L], winS[L], Wl);
      O.w = enc(xcv.y, ycv.y, winO[L], winS[L], Wl);
      wt[p * 3 + L] = Wt;
      ot[p * 3 + L] = O;
    }
  }
}

template <int L>
__device__ __forceinline__ float tapval(const float* __restrict__ x,
                                        const float* __restrict__ Vb, int off, int b,
                                        int c) {
  if (off >= 0) return Vb[off + c];
  int code = -1 - off;
  constexpr int Wl = 64 >> L;
  int yc = code >> (6 - L);
  int xcv = code & (Wl - 1);
  return boxavg<L>(x, b, c, yc, xcv);
}

template <int L, int S>
__device__ __forceinline__ float level_fast(const float* __restrict__ x,
                                            const float* __restrict__ ws,
                                            const float4* __restrict__ wtab,
                                            const int4* __restrict__ otab,
                                            const float* __restrict__ FT, long offV,
                                            int b, int p, int lane) {
  float4 Wt = wtab[p * 3 + L];
  int4 Ot = otab[p * 3 + L];
  float F = FT[(long)p * 192 + L * 64 + lane];
  const float* Vb = ws + offV + (long)b * (S * S * 64);
  float s = Wt.x * tapval<L>(x, Vb, Ot.x, b, lane);
  s += Wt.y * tapval<L>(x, Vb, Ot.y, b, lane);
  s += Wt.z * tapval<L>(x, Vb, Ot.z, b, lane);
  s += Wt.w * tapval<L>(x, Vb, Ot.w, b, lane);
  return F * s;
}

template <bool FAST>
__global__ __launch_bounds__(256) void st_main(const float* __restrict__ x,
                                               const float* __restrict__ grid,
                                               const float* __restrict__ features,
                                               const float* __restrict__ bias,
                                               const float* __restrict__ ws,
                                               float* __restrict__ out) {
  const int tid = threadIdx.x;
  const int lane = tid & 63;
  const int wv = tid >> 6;
  const int b = blockIdx.x >> 3;     // 256 images
  const int chunk = blockIdx.x & 7;  // 8 chunks of 256 points
  const float4* wtab = (const float4*)(ws + OFF_WT);
  const int4* otab = (const int4*)(ws + OFF_OT);
  const float* FT = ws + OFF_FT;
  const int pbase = chunk * 256 + wv * 64;
  for (int pi = 0; pi < 64; ++pi) {
    const int p = pbase + pi;
    float acc = 0.f;
    if constexpr (FAST) {
      acc += level_fast<0, 16>(x, ws, wtab, otab, FT, OFF_V0, b, p, lane);
      acc += level_fast<1, 8>(x, ws, wtab, otab, FT, OFF_V1, b, p, lane);
      acc += level_fast<2, 4>(x, ws, wtab, otab, FT, OFF_V2, b, p, lane);
    } else {
      // correctness-only path (ws too small): everything on the fly
      float gx = fminf(fmaxf(grid[2 * p], -1.f), 1.f);
      float gy = fminf(fmaxf(grid[2 * p + 1], -1.f), 1.f);
      float4 Wt;
      int2 xcv, ycv;
      taps_for(gx, gy, 64, Wt, xcv, ycv);
      float F = features[(long)(0 * 64 + lane) * 2048 + p];
      float s = Wt.x * boxavg<0>(x, b, lane, ycv.x, xcv.x) +
                Wt.y * boxavg<0>(x, b, lane, ycv.x, xcv.y) +
                Wt.z * boxavg<0>(x, b, lane, ycv.y, xcv.x) +
                Wt.w * boxavg<0>(x, b, lane, ycv.y, xcv.y);
      acc += F * s;
      taps_for(gx, gy, 32, Wt, xcv, ycv);
      F = features[(long)(64 + lane) * 2048 + p];
      s = Wt.x * boxavg<1>(x, b, lane, ycv.x, xcv.x) +
          Wt.y * boxavg<1>(x, b, lane, ycv.x, xcv.y) +
          Wt.z * boxavg<1>(x, b, lane, ycv.y, xcv.x) +
          Wt.w * boxavg<1>(x, b, lane, ycv.y, xcv.y);
      acc += F * s;
      taps_for(gx, gy, 16, Wt, xcv, ycv);
      F = features[(long)(128 + lane) * 2048 + p];
      s = Wt.x * boxavg<2>(x, b, lane, ycv.x, xcv.x) +
          Wt.y * boxavg<2>(x, b, lane, ycv.x, xcv.y) +
          Wt.z * boxavg<2>(x, b, lane, ycv.y, xcv.x) +
          Wt.w * boxavg<2>(x, b, lane, ycv.y, xcv.y);
      acc += F * s;
    }
#pragma unroll
    for (int d = 32; d > 0; d >>= 1) acc += __shfl_xor(acc, d, 64);
    if (lane == 0) out[b * P_ + p] = acc + bias[p];
  }
}

}  // namespace

extern "C" void kernel_launch(void* const* d_in, const int* in_sizes, int n_in,
                              void* d_out, int out_size, void* d_ws, size_t ws_size,
                              hipStream_t stream) {
  const float* x = (const float*)d_in[0];
  const float* grid = (const float*)d_in[1];
  const float* features = (const float*)d_in[2];
  const float* bias = (const float*)d_in[3];
  float* out = (float*)d_out;
  float* ws = (float*)d_ws;

  if (ws_size >= WS_BYTES) {
    constexpr long total = NV0 + NV1 + NV2 + NFT + P_;
    constexpr int nblk = (int)((total + 255) / 256);
    st_prep<<<nblk, 256, 0, stream>>>(x, grid, features, ws);
    st_main<true><<<2048, 256, 0, stream>>>(x, grid, features, bias, ws, out);
  } else {
    st_main<false><<<2048, 256, 0, stream>>>(x, grid, features, bias, nullptr, out);
  }
}

// Round 2
// 156.740 us; speedup vs baseline: 1.3547x; 1.3547x over previous
//
#include <hip/hip_runtime.h>

// SpatialTransformerPooled3d: x(16,64,16,64,64) f32, grid(1,2048,1,2),
// features(1,192,1,2048), bias(2048) -> out(16,16,2048) f32.
// b = n*16+t indexes 256 images of 64ch x 64x64.
// out[b,p] = bias[p] + sum_l sum_c feat[l*64+c,p] * bilinear_l(img_l[b,c], pts[p])
//
// Design: grid values are tiny (+-0.05) so all taps hit a small central
// window at each pyramid level. prep_v extracts per-b padded windows
// (l0 8x8 @ [28,36), l1 4x4 @ [14,18), l2 4x4 @ [6,10)) into ws; st_main
// stages the 29.4KB per-b window set into LDS and evaluates 2048 points
// with 6 ds_read2-class loads per point. Out-of-window taps (never hit for
// the bench grid, but required for generality) take an exact per-level
// fallback that samples x directly.

namespace {

constexpr int P_ = 2048;
constexpr int B_ = 256;

// per-b V layout (dword units). Odd per-channel strides -> gcd(stride,32)=1
// -> conflict-free lane=c LDS reads.
constexpr int V0_C = 73;                 // 8 rows * 9 (padded) + 1
constexpr int V1_C = 21;                 // 4 rows * 5 (padded) + 1
constexpr int V0_SZ = 64 * V0_C;         // 4672
constexpr int V1_OFF = V0_SZ;            // 4672
constexpr int V1_SZ = 64 * V1_C;         // 1344
constexpr int V2_OFF = V1_OFF + V1_SZ;   // 6016
constexpr int VB_SZ = V2_OFF + V1_SZ;    // 7360 dwords = 29440 B

// window origins (in level coords) and fast-path sizes
constexpr int ORG0 = 28, SZ0 = 8, PAD0 = 9;
constexpr int ORG1 = 14, SZ1 = 4, PAD1 = 5;
constexpr int ORG2 = 6,  SZ2 = 4, PAD2 = 5;

// ws layout (dwords)
constexpr long OFF_V = 0;
constexpr long NV = (long)B_ * VB_SZ;        // 1,884,160
constexpr long OFF_FT = OFF_V + NV;          // FT[p*192 + (L*64+c)]
constexpr long NFT = (long)P_ * 192;         // 393,216
constexpr long OFF_TAB = OFF_FT + NFT;       // float4 TAB[p*4 + {w0,w1,w2,off}]
constexpr long NTAB = (long)P_ * 16;
constexpr long WS_DW = OFF_TAB + NTAB;
constexpr size_t WS_BYTES = (size_t)WS_DW * 4;

__device__ __forceinline__ int xoff(int b, int c, int y, int xc) {
  // x index (n, c, t, y, xc); b = n*16 + t
  int n = b >> 4, t = b & 15;
  return (((n * 64 + c) * 16 + t) << 12) + (y << 6) + xc;
}

template <int L>
__device__ __forceinline__ float boxavg(const float* __restrict__ x, int b, int c,
                                        int yc, int xc) {
  constexpr int s = 1 << L;
  int base = xoff(b, c, yc * s, xc * s);
  float sum = 0.f;
#pragma unroll
  for (int dy = 0; dy < s; ++dy)
#pragma unroll
    for (int dx = 0; dx < s; ++dx) sum += x[base + dy * 64 + dx];
  return sum * (1.0f / (s * s));
}

// Full reference-exact taps (validity folded into weights, clamped coords).
__device__ __forceinline__ void taps_for(float gx, float gy, int Wl, float4& Wt,
                                         int2& xcv, int2& ycv) {
  float ix = ((gx + 1.f) * Wl - 1.f) * 0.5f;
  float iy = ((gy + 1.f) * Wl - 1.f) * 0.5f;
  float ix0f = floorf(ix), iy0f = floorf(iy);
  float fx1 = ix - ix0f, fy1 = iy - iy0f;
  float fx0 = 1.f - fx1, fy0 = 1.f - fy1;
  int ix0 = (int)ix0f, iy0 = (int)iy0f;
  int ix1 = ix0 + 1, iy1 = iy0 + 1;
  bool vx0 = (ix0 >= 0) && (ix0 < Wl);
  bool vx1 = (ix1 >= 0) && (ix1 < Wl);
  bool vy0 = (iy0 >= 0) && (iy0 < Wl);
  bool vy1 = (iy1 >= 0) && (iy1 < Wl);
  xcv.x = min(max(ix0, 0), Wl - 1);
  xcv.y = min(max(ix1, 0), Wl - 1);
  ycv.x = min(max(iy0, 0), Wl - 1);
  ycv.y = min(max(iy1, 0), Wl - 1);
  Wt.x = (vx0 && vy0) ? fx0 * fy0 : 0.f;
  Wt.y = (vx1 && vy0) ? fx1 * fy0 : 0.f;
  Wt.z = (vx0 && vy1) ? fx0 * fy1 : 0.f;
  Wt.w = (vx1 && vy1) ? fx1 * fy1 : 0.f;
}

// Exact per-level fallback sample (channel = c) straight from x.
template <int L>
__device__ float slow_level(const float* __restrict__ x, const float* __restrict__ grid,
                            int b, int p, int c) {
  float gx = fminf(fmaxf(grid[2 * p], -1.f), 1.f);
  float gy = fminf(fmaxf(grid[2 * p + 1], -1.f), 1.f);
  float4 Wt;
  int2 xcv, ycv;
  taps_for(gx, gy, 64 >> L, Wt, xcv, ycv);
  return Wt.x * boxavg<L>(x, b, c, ycv.x, xcv.x) +
         Wt.y * boxavg<L>(x, b, c, ycv.x, xcv.y) +
         Wt.z * boxavg<L>(x, b, c, ycv.y, xcv.x) +
         Wt.w * boxavg<L>(x, b, c, ycv.y, xcv.y);
}

// ---------------- prep: build per-b padded windows into ws ----------------
__global__ __launch_bounds__(256) void st_prep_v(const float* __restrict__ x,
                                                 float* __restrict__ ws) {
  int idx = blockIdx.x * 256 + threadIdx.x;
  if (idx < 1048576) {  // V0: straight copy of [28,36)^2
    int xx = idx & 7, yy = (idx >> 3) & 7, c = (idx >> 6) & 63, b = idx >> 12;
    ws[(long)b * VB_SZ + c * V0_C + yy * PAD0 + xx] = x[xoff(b, c, 28 + yy, 28 + xx)];
    return;
  }
  idx -= 1048576;
  if (idx < 262144) {  // V1: 2x2 mean, window [14,18)^2 (source [28,36)^2)
    int xx = idx & 3, yy = (idx >> 2) & 3, c = (idx >> 4) & 63, b = idx >> 10;
    int base = xoff(b, c, 28 + 2 * yy, 28 + 2 * xx);
    ws[(long)b * VB_SZ + V1_OFF + c * V1_C + yy * PAD1 + xx] =
        0.25f * (x[base] + x[base + 1] + x[base + 64] + x[base + 65]);
    return;
  }
  idx -= 262144;
  if (idx < 262144) {  // V2: 4x4 mean, window [6,10)^2 (source [24,40)^2)
    int xx = idx & 3, yy = (idx >> 2) & 3, c = (idx >> 4) & 63, b = idx >> 10;
    int base = xoff(b, c, 24 + 4 * yy, 24 + 4 * xx);
    float s = 0.f;
#pragma unroll
    for (int dy = 0; dy < 4; ++dy)
#pragma unroll
      for (int dx = 0; dx < 4; ++dx) s += x[base + dy * 64 + dx];
    ws[(long)b * VB_SZ + V2_OFF + c * V1_C + yy * PAD1 + xx] = s * (1.f / 16.f);
  }
}

// ---------------- prep: features transpose (LDS tiles) + tap tables -------
__global__ __launch_bounds__(256) void st_ft(const float* __restrict__ grid,
                                             const float* __restrict__ features,
                                             float* __restrict__ ws) {
  __shared__ float tile[64][65];
  const int blk = blockIdx.x;
  const int tid = threadIdx.x;
  if (blk < 96) {  // 32 p-tiles x 3 lc-tiles of 64x64
    const int pt = blk & 31, lt = blk >> 5;
    const int col = tid & 63, r4 = tid >> 6;
#pragma unroll
    for (int i = 0; i < 16; ++i) {
      int row = i * 4 + r4;
      tile[row][col] = features[(long)(lt * 64 + row) * 2048 + pt * 64 + col];
    }
    __syncthreads();
#pragma unroll
    for (int i = 0; i < 16; ++i) {
      int pl = i * 4 + r4;
      ws[OFF_FT + (long)(pt * 64 + pl) * 192 + lt * 64 + col] = tile[col][pl];
    }
    return;
  }
  // tap tables: one thread per point x 8
  for (int k = 0; k < 8; ++k) {
    int p = k * 256 + tid;
    float gx = fminf(fmaxf(grid[2 * p], -1.f), 1.f);
    float gy = fminf(fmaxf(grid[2 * p + 1], -1.f), 1.f);
    float4* T = (float4*)(ws + OFF_TAB) + (long)p * 4;
    int off[3];
    const int org[3] = {ORG0, ORG1, ORG2};
    const int sz[3] = {SZ0, SZ1, SZ2};
    const int pad[3] = {PAD0, PAD1, PAD2};
#pragma unroll
    for (int L = 0; L < 3; ++L) {
      int Wl = 64 >> L;
      float ix = ((gx + 1.f) * Wl - 1.f) * 0.5f;
      float iy = ((gy + 1.f) * Wl - 1.f) * 0.5f;
      float ix0f = floorf(ix), iy0f = floorf(iy);
      float fx1 = ix - ix0f, fy1 = iy - iy0f;
      float fx0 = 1.f - fx1, fy0 = 1.f - fy1;
      int ix0 = (int)ix0f, iy0 = (int)iy0f;
      bool fast = (ix0 >= org[L]) && (ix0 + 1 <= org[L] + sz[L] - 1) &&
                  (iy0 >= org[L]) && (iy0 + 1 <= org[L] + sz[L] - 1);
      off[L] = fast ? (iy0 - org[L]) * pad[L] + (ix0 - org[L]) : -1;
      T[L] = make_float4(fx0 * fy0, fx1 * fy0, fx0 * fy1, fx1 * fy1);
    }
    T[3] = make_float4(__int_as_float(off[0]), __int_as_float(off[1]),
                       __int_as_float(off[2]), 0.f);
  }
}

// ---------------- main: LDS-staged sampling -------------------------------
__global__ __launch_bounds__(512) void st_main(const float* __restrict__ x,
                                               const float* __restrict__ grid,
                                               const float* __restrict__ bias,
                                               const float* __restrict__ ws,
                                               float* __restrict__ out) {
  __shared__ float S[VB_SZ];
  const int tid = threadIdx.x;
  const int b = blockIdx.x >> 2, q = blockIdx.x & 3;
  const float* Vb = ws + (long)b * VB_SZ;
  for (int i = tid; i < VB_SZ; i += 512) S[i] = Vb[i];
  __syncthreads();
  const int lane = tid & 63, wv = tid >> 6;
  const int cb0 = lane * V0_C;
  const int cb1 = V1_OFF + lane * V1_C;
  const int cb2 = V2_OFF + lane * V1_C;
  const float* FT = ws + OFF_FT;
  const float4* TAB = (const float4*)(ws + OFF_TAB);
  const int pbase = q * 512 + wv * 64;
#pragma unroll 2
  for (int pi = 0; pi < 64; ++pi) {
    const int p = pbase + pi;
    const float4 w0 = TAB[p * 4 + 0];
    const float4 w1 = TAB[p * 4 + 1];
    const float4 w2 = TAB[p * 4 + 2];
    const float4 of = TAB[p * 4 + 3];
    const int o0 = __float_as_int(of.x);
    const int o1 = __float_as_int(of.y);
    const int o2 = __float_as_int(of.z);
    const float F0 = FT[p * 192 + lane];
    const float F1 = FT[p * 192 + 64 + lane];
    const float F2 = FT[p * 192 + 128 + lane];
    float acc;
    if (o0 >= 0) {
      int a = cb0 + o0;
      float s = w0.x * S[a] + w0.y * S[a + 1] + w0.z * S[a + PAD0] + w0.w * S[a + PAD0 + 1];
      acc = F0 * s;
    } else {
      acc = F0 * slow_level<0>(x, grid, b, p, lane);
    }
    if (o1 >= 0) {
      int a = cb1 + o1;
      float s = w1.x * S[a] + w1.y * S[a + 1] + w1.z * S[a + PAD1] + w1.w * S[a + PAD1 + 1];
      acc = fmaf(F1, s, acc);
    } else {
      acc = fmaf(F1, slow_level<1>(x, grid, b, p, lane), acc);
    }
    if (o2 >= 0) {
      int a = cb2 + o2;
      float s = w2.x * S[a] + w2.y * S[a + 1] + w2.z * S[a + PAD2] + w2.w * S[a + PAD2 + 1];
      acc = fmaf(F2, s, acc);
    } else {
      acc = fmaf(F2, slow_level<2>(x, grid, b, p, lane), acc);
    }
#pragma unroll
    for (int d = 32; d > 0; d >>= 1) acc += __shfl_xor(acc, d, 64);
    if (lane == 0) out[(long)b * P_ + p] = acc + bias[p];
  }
}

// ---------------- fallback (ws too small; exact, slow) --------------------
__global__ __launch_bounds__(256) void st_fallback(const float* __restrict__ x,
                                                   const float* __restrict__ grid,
                                                   const float* __restrict__ features,
                                                   const float* __restrict__ bias,
                                                   float* __restrict__ out) {
  const int tid = threadIdx.x;
  const int lane = tid & 63, wv = tid >> 6;
  const int b = blockIdx.x >> 3, chunk = blockIdx.x & 7;
  const int pbase = chunk * 256 + wv * 64;
  for (int pi = 0; pi < 64; ++pi) {
    const int p = pbase + pi;
    float acc = features[(long)(0 + lane) * 2048 + p] * slow_level<0>(x, grid, b, p, lane);
    acc = fmaf(features[(long)(64 + lane) * 2048 + p], slow_level<1>(x, grid, b, p, lane), acc);
    acc = fmaf(features[(long)(128 + lane) * 2048 + p], slow_level<2>(x, grid, b, p, lane), acc);
#pragma unroll
    for (int d = 32; d > 0; d >>= 1) acc += __shfl_xor(acc, d, 64);
    if (lane == 0) out[(long)b * P_ + p] = acc + bias[p];
  }
}

}  // namespace

extern "C" void kernel_launch(void* const* d_in, const int* in_sizes, int n_in,
                              void* d_out, int out_size, void* d_ws, size_t ws_size,
                              hipStream_t stream) {
  const float* x = (const float*)d_in[0];
  const float* grid = (const float*)d_in[1];
  const float* features = (const float*)d_in[2];
  const float* bias = (const float*)d_in[3];
  float* out = (float*)d_out;
  float* ws = (float*)d_ws;

  if (ws_size >= WS_BYTES) {
    st_prep_v<<<6144, 256, 0, stream>>>(x, ws);
    st_ft<<<97, 256, 0, stream>>>(grid, features, ws);
    st_main<<<1024, 512, 0, stream>>>(x, grid, bias, ws, out);
  } else {
    st_fallback<<<2048, 256, 0, stream>>>(x, grid, features, bias, out);
  }
}

// Round 3
// 60.619 us; speedup vs baseline: 3.5028x; 2.5857x over previous
//
#include <hip/hip_runtime.h>

// SpatialTransformerPooled3d: x(16,64,16,64,64) f32, grid(1,2048,1,2),
// features(1,192,1,2048), bias(2048) -> out(16,16,2048) f32.
// b = n*16+t indexes 256 images of 64ch x 64x64.
// out[b,p] = bias[p] + sum_l sum_c feat[l*64+c,p] * bilinear_l(img_l[b,c], pts[p])
//
// R2 design: lane = point (no cross-lane reduction), loop over channels.
// Grid values are tiny (+-0.05) so all taps hit a small central window at
// each level; prep extracts per-b padded windows (l0 8x8 @ [28,36),
// l1 4x4 @ [14,18), l2 4x4 @ [6,10)) into ws. st_main stages the 29.4KB
// per-b window set into LDS; each thread owns one (b,p) output and
// accumulates 64 channels x 3 levels with ds_read2-class LDS reads
// (c is wave-uniform -> conflicts governed by tap-offset spread: ~2-way
// max, l2 is pure broadcast). features reads are stride-1 coalesced in the
// ORIGINAL layout (no transpose needed). Out-of-window taps (never hit for
// the bench grid) take an exact per-lane fallback straight from x.

namespace {

constexpr int P_ = 2048;
constexpr int B_ = 256;

// per-b V window layout (dword units)
constexpr int V0_C = 73;                 // 8 rows * 9 (padded) + 1
constexpr int V1_C = 21;                 // 4 rows * 5 (padded) + 1
constexpr int V0_SZ = 64 * V0_C;         // 4672
constexpr int V1_OFF = V0_SZ;            // 4672
constexpr int V1_SZ = 64 * V1_C;         // 1344
constexpr int V2_OFF = V1_OFF + V1_SZ;   // 6016
constexpr int VB_SZ = V2_OFF + V1_SZ;    // 7360 dwords = 29440 B

// window origins (level coords), sizes, row pads
constexpr int ORG0 = 28, SZ0 = 8, PAD0 = 9;
constexpr int ORG1 = 14, SZ1 = 4, PAD1 = 5;
constexpr int ORG2 = 6,  SZ2 = 4, PAD2 = 5;

// ws layout (dwords)
constexpr long NV = (long)B_ * VB_SZ;     // 1,884,160
constexpr long OFF_TAB = NV;              // float4 TAB[p*4 + {w0,w1,w2,offs}]
constexpr long NTAB = (long)P_ * 16;
constexpr long WS_DW = OFF_TAB + NTAB;
constexpr size_t WS_BYTES = (size_t)WS_DW * 4;

__device__ __forceinline__ int xoff(int b, int c, int y, int xc) {
  // x index (n, c, t, y, xc); b = n*16 + t
  int n = b >> 4, t = b & 15;
  return (((n * 64 + c) * 16 + t) << 12) + (y << 6) + xc;
}

template <int L>
__device__ __forceinline__ float boxavg(const float* __restrict__ x, int b, int c,
                                        int yc, int xc) {
  constexpr int s = 1 << L;
  int base = xoff(b, c, yc * s, xc * s);
  float sum = 0.f;
#pragma unroll
  for (int dy = 0; dy < s; ++dy)
#pragma unroll
    for (int dx = 0; dx < s; ++dx) sum += x[base + dy * 64 + dx];
  return sum * (1.0f / (s * s));
}

// Reference-exact taps (validity folded into weights, clamped coords).
__device__ __forceinline__ void taps_for(float gx, float gy, int Wl, float4& Wt,
                                         int2& xcv, int2& ycv) {
  float ix = ((gx + 1.f) * Wl - 1.f) * 0.5f;
  float iy = ((gy + 1.f) * Wl - 1.f) * 0.5f;
  float ix0f = floorf(ix), iy0f = floorf(iy);
  float fx1 = ix - ix0f, fy1 = iy - iy0f;
  float fx0 = 1.f - fx1, fy0 = 1.f - fy1;
  int ix0 = (int)ix0f, iy0 = (int)iy0f;
  int ix1 = ix0 + 1, iy1 = iy0 + 1;
  bool vx0 = (ix0 >= 0) && (ix0 < Wl);
  bool vx1 = (ix1 >= 0) && (ix1 < Wl);
  bool vy0 = (iy0 >= 0) && (iy0 < Wl);
  bool vy1 = (iy1 >= 0) && (iy1 < Wl);
  xcv.x = min(max(ix0, 0), Wl - 1);
  xcv.y = min(max(ix1, 0), Wl - 1);
  ycv.x = min(max(iy0, 0), Wl - 1);
  ycv.y = min(max(iy1, 0), Wl - 1);
  Wt.x = (vx0 && vy0) ? fx0 * fy0 : 0.f;
  Wt.y = (vx1 && vy0) ? fx1 * fy0 : 0.f;
  Wt.z = (vx0 && vy1) ? fx0 * fy1 : 0.f;
  Wt.w = (vx1 && vy1) ? fx1 * fy1 : 0.f;
}

// Exact per-level fallback sample (channel c) straight from x.
template <int L>
__device__ float slow_level(const float* __restrict__ x, const float* __restrict__ grid,
                            int b, int p, int c) {
  float gx = fminf(fmaxf(grid[2 * p], -1.f), 1.f);
  float gy = fminf(fmaxf(grid[2 * p + 1], -1.f), 1.f);
  float4 Wt;
  int2 xcv, ycv;
  taps_for(gx, gy, 64 >> L, Wt, xcv, ycv);
  return Wt.x * boxavg<L>(x, b, c, ycv.x, xcv.x) +
         Wt.y * boxavg<L>(x, b, c, ycv.x, xcv.y) +
         Wt.z * boxavg<L>(x, b, c, ycv.y, xcv.x) +
         Wt.w * boxavg<L>(x, b, c, ycv.y, xcv.y);
}

// ------------- prep: per-b padded windows + per-point tap tables ----------
__global__ __launch_bounds__(256) void st_prep(const float* __restrict__ x,
                                               const float* __restrict__ grid,
                                               float* __restrict__ ws) {
  int idx = blockIdx.x * 256 + threadIdx.x;
  if (idx < 1048576) {  // V0: straight copy of [28,36)^2
    int xx = idx & 7, yy = (idx >> 3) & 7, c = (idx >> 6) & 63, b = idx >> 12;
    ws[(long)b * VB_SZ + c * V0_C + yy * PAD0 + xx] = x[xoff(b, c, 28 + yy, 28 + xx)];
    return;
  }
  idx -= 1048576;
  if (idx < 262144) {  // V1: 2x2 mean, window [14,18)^2 (source [28,36)^2)
    int xx = idx & 3, yy = (idx >> 2) & 3, c = (idx >> 4) & 63, b = idx >> 10;
    int base = xoff(b, c, 28 + 2 * yy, 28 + 2 * xx);
    ws[(long)b * VB_SZ + V1_OFF + c * V1_C + yy * PAD1 + xx] =
        0.25f * (x[base] + x[base + 1] + x[base + 64] + x[base + 65]);
    return;
  }
  idx -= 262144;
  if (idx < 262144) {  // V2: 4x4 mean, window [6,10)^2 (source [24,40)^2)
    int xx = idx & 3, yy = (idx >> 2) & 3, c = (idx >> 4) & 63, b = idx >> 10;
    int base = xoff(b, c, 24 + 4 * yy, 24 + 4 * xx);
    float s = 0.f;
#pragma unroll
    for (int dy = 0; dy < 4; ++dy)
#pragma unroll
      for (int dx = 0; dx < 4; ++dx) s += x[base + dy * 64 + dx];
    ws[(long)b * VB_SZ + V2_OFF + c * V1_C + yy * PAD1 + xx] = s * (1.f / 16.f);
    return;
  }
  idx -= 262144;
  if (idx < P_) {  // tap tables, one thread per point
    int p = idx;
    float gx = fminf(fmaxf(grid[2 * p], -1.f), 1.f);
    float gy = fminf(fmaxf(grid[2 * p + 1], -1.f), 1.f);
    float4* T = (float4*)(ws + OFF_TAB) + (long)p * 4;
    int off[3];
    const int org[3] = {ORG0, ORG1, ORG2};
    const int sz[3] = {SZ0, SZ1, SZ2};
    const int pad[3] = {PAD0, PAD1, PAD2};
#pragma unroll
    for (int L = 0; L < 3; ++L) {
      int Wl = 64 >> L;
      float ix = ((gx + 1.f) * Wl - 1.f) * 0.5f;
      float iy = ((gy + 1.f) * Wl - 1.f) * 0.5f;
      float ix0f = floorf(ix), iy0f = floorf(iy);
      float fx1 = ix - ix0f, fy1 = iy - iy0f;
      float fx0 = 1.f - fx1, fy0 = 1.f - fy1;
      int ix0 = (int)ix0f, iy0 = (int)iy0f;
      // fast iff the 2x2 tap footprint is fully inside the window (interior
      // => no clamping, all validity masks true)
      bool fast = (ix0 >= org[L]) && (ix0 + 1 <= org[L] + sz[L] - 1) &&
                  (iy0 >= org[L]) && (iy0 + 1 <= org[L] + sz[L] - 1);
      off[L] = fast ? (iy0 - org[L]) * pad[L] + (ix0 - org[L]) : -1;
      T[L] = make_float4(fx0 * fy0, fx1 * fy0, fx0 * fy1, fx1 * fy1);
    }
    T[3] = make_float4(__int_as_float(off[0]), __int_as_float(off[1]),
                       __int_as_float(off[2]), 0.f);
  }
}

// ------------- main: lane = point, accumulate over channels ---------------
__global__ __launch_bounds__(512) void st_main(const float* __restrict__ x,
                                               const float* __restrict__ grid,
                                               const float* __restrict__ features,
                                               const float* __restrict__ bias,
                                               const float* __restrict__ ws,
                                               float* __restrict__ out) {
  __shared__ float S[VB_SZ];
  const int tid = threadIdx.x;
  const int b = blockIdx.x >> 2, q = blockIdx.x & 3;
  const float* Vb = ws + (long)b * VB_SZ;
  for (int i = tid; i < VB_SZ; i += 512) S[i] = Vb[i];
  __syncthreads();

  const int p = q * 512 + tid;  // this thread's point
  const float4* T = (const float4*)(ws + OFF_TAB) + (long)p * 4;
  const float4 w0 = T[0], w1 = T[1], w2 = T[2], of = T[3];
  int o0 = __float_as_int(of.x), o1 = __float_as_int(of.y), o2 = __float_as_int(of.z);
  const bool ok = (o0 >= 0) && (o1 >= 0) && (o2 >= 0);
  o0 = max(o0, 0);  // keep LDS reads in-bounds for !ok lanes (result discarded)
  o1 = max(o1, 0);
  o2 = max(o2, 0);

  const float* f0 = features + p;               // + c*2048 : coalesced
  const float* f1 = features + 64 * 2048 + p;
  const float* f2 = features + 128 * 2048 + p;
  const float* S0 = S + o0;
  const float* S1 = S + V1_OFF + o1;
  const float* S2 = S + V2_OFF + o2;

  float acc = 0.f;
#pragma unroll 4
  for (int c = 0; c < 64; ++c) {
    const float F0 = f0[c * 2048];
    const float F1 = f1[c * 2048];
    const float F2 = f2[c * 2048];
    const float* a0 = S0 + c * V0_C;
    const float* a1 = S1 + c * V1_C;
    const float* a2 = S2 + c * V1_C;
    float s0 = w0.x * a0[0] + w0.y * a0[1] + w0.z * a0[PAD0] + w0.w * a0[PAD0 + 1];
    float s1 = w1.x * a1[0] + w1.y * a1[1] + w1.z * a1[PAD1] + w1.w * a1[PAD1 + 1];
    float s2 = w2.x * a2[0] + w2.y * a2[1] + w2.z * a2[PAD2] + w2.w * a2[PAD2 + 1];
    acc = fmaf(F0, s0, acc);
    acc = fmaf(F1, s1, acc);
    acc = fmaf(F2, s2, acc);
  }

  if (!ok) {  // exact per-lane fallback (never taken for the bench grid)
    acc = 0.f;
    for (int c = 0; c < 64; ++c) {
      acc = fmaf(f0[c * 2048], slow_level<0>(x, grid, b, p, c), acc);
      acc = fmaf(f1[c * 2048], slow_level<1>(x, grid, b, p, c), acc);
      acc = fmaf(f2[c * 2048], slow_level<2>(x, grid, b, p, c), acc);
    }
  }
  out[(long)b * P_ + p] = acc + bias[p];
}

// ------------- fallback (ws too small; exact, slow) -----------------------
__global__ __launch_bounds__(256) void st_fallback(const float* __restrict__ x,
                                                   const float* __restrict__ grid,
                                                   const float* __restrict__ features,
                                                   const float* __restrict__ bias,
                                                   float* __restrict__ out) {
  const int tid = threadIdx.x;
  const int lane = tid & 63, wv = tid >> 6;
  const int b = blockIdx.x >> 3, chunk = blockIdx.x & 7;
  const int pbase = chunk * 256 + wv * 64;
  for (int pi = 0; pi < 64; ++pi) {
    const int p = pbase + pi;
    float acc = features[(long)lane * 2048 + p] * slow_level<0>(x, grid, b, p, lane);
    acc = fmaf(features[(long)(64 + lane) * 2048 + p], slow_level<1>(x, grid, b, p, lane), acc);
    acc = fmaf(features[(long)(128 + lane) * 2048 + p], slow_level<2>(x, grid, b, p, lane), acc);
#pragma unroll
    for (int d = 32; d > 0; d >>= 1) acc += __shfl_xor(acc, d, 64);
    if (lane == 0) out[(long)b * P_ + p] = acc + bias[p];
  }
}

}  // namespace

extern "C" void kernel_launch(void* const* d_in, const int* in_sizes, int n_in,
                              void* d_out, int out_size, void* d_ws, size_t ws_size,
                              hipStream_t stream) {
  const float* x = (const float*)d_in[0];
  const float* grid = (const float*)d_in[1];
  const float* features = (const float*)d_in[2];
  const float* bias = (const float*)d_in[3];
  float* out = (float*)d_out;
  float* ws = (float*)d_ws;

  if (ws_size >= WS_BYTES) {
    // 1,572,864 window elements + 2048 tap-table points, 256 thr/blk
    st_prep<<<6152, 256, 0, stream>>>(x, grid, ws);
    st_main<<<1024, 512, 0, stream>>>(x, grid, features, bias, ws, out);
  } else {
    st_fallback<<<2048, 256, 0, stream>>>(x, grid, features, bias, out);
  }
}